// Round 10
// baseline (211.286 us; speedup 1.0000x reference)
//
#include <hip/hip_runtime.h>

#define S_  4096
#define HD_ 64
#define H_  4
#define B_  2
#define DM  256
#define NS  4                 // split-K factor for attention
#define KSPAN (S_ / NS)       // 1024
#define NITER (KSPAN / 64)    // 16

typedef __bf16 bf16x8 __attribute__((ext_vector_type(8)));
typedef __bf16 bf16x4 __attribute__((ext_vector_type(4)));
typedef float  f32x4  __attribute__((ext_vector_type(4)));
typedef unsigned u32x4 __attribute__((ext_vector_type(4)));
typedef unsigned long long u64;

__device__ __forceinline__ bf16x8 cvt8(const float* p) {
    float4 u0 = *reinterpret_cast<const float4*>(p);
    float4 u1 = *reinterpret_cast<const float4*>(p + 4);
    bf16x8 r = { (__bf16)u0.x, (__bf16)u0.y, (__bf16)u0.z, (__bf16)u0.w,
                 (__bf16)u1.x, (__bf16)u1.y, (__bf16)u1.z, (__bf16)u1.w };
    return r;
}

__device__ __forceinline__ unsigned pk2(float a, float b) {
    unsigned la = (unsigned)__builtin_bit_cast(unsigned short, (__bf16)a);
    unsigned lb = (unsigned)__builtin_bit_cast(unsigned short, (__bf16)b);
    return la | (lb << 16);
}

// ---------------- fused: mask bit-pack [0,1024) + QKV proj (f32 W) [1024,1792) + Wo cast [1792,1808) ----------------
// packed[kbb*S + q] bit layout: bitpos(col) = (col&3)*16 + (col>>2)
__global__ __launch_bounds__(256) void fused_prep_kernel(const int* __restrict__ mask,
                                                         u64* __restrict__ packed,
                                                         const float* __restrict__ xl,
                                                         const float* __restrict__ xm,
                                                         const float* __restrict__ Wq,
                                                         const float* __restrict__ Wk,
                                                         const float* __restrict__ Wv,
                                                         const float* __restrict__ Wo,
                                                         const float* __restrict__ bq,
                                                         const float* __restrict__ bk,
                                                         const float* __restrict__ bv,
                                                         __bf16* __restrict__ Qb,
                                                         __bf16* __restrict__ Kb,
                                                         __bf16* __restrict__ Vtb,
                                                         __bf16* __restrict__ wob) {
    const int bid = blockIdx.x;
    if (bid < 1024) {
        // ---- mask packing (round-7 proven path: 4-batched independent loads) ----
        const int gw   = bid * 4 + (threadIdx.x >> 6);  // [0,4096)
        const int lane = threadIdx.x & 63;
        const int r  = lane >> 4;       // q sub-row 0..3
        const int ll = lane & 15;       // col-quad index
#pragma unroll
        for (int sb = 0; sb < 4; ++sb) {
            int4 v[4];
#pragma unroll
            for (int j = 0; j < 4; ++j) {
                const int u   = gw + (sb * 4 + j) * 4096;   // unit [0,65536)
                const int kbb = u & 63;
                const int q0  = (u >> 6) * 4;
                v[j] = *reinterpret_cast<const int4*>(
                    mask + (size_t)(q0 + r) * S_ + kbb * 64 + ll * 4);
            }
#pragma unroll
            for (int j = 0; j < 4; ++j) {
                const int u   = gw + (sb * 4 + j) * 4096;
                const int kbb = u & 63;
                const int q0  = (u >> 6) * 4;
                const u64 b0 = __ballot(v[j].x != 0);
                const u64 b1 = __ballot(v[j].y != 0);
                const u64 b2 = __ballot(v[j].z != 0);
                const u64 b3 = __ballot(v[j].w != 0);
                if (ll == 0) {
                    const u64 word = ((b0 >> (16 * r)) & 0xFFFFull)
                                   | (((b1 >> (16 * r)) & 0xFFFFull) << 16)
                                   | (((b2 >> (16 * r)) & 0xFFFFull) << 32)
                                   | (((b3 >> (16 * r)) & 0xFFFFull) << 48);
                    packed[(size_t)kbb * S_ + q0 + r] = word;
                }
            }
        }
        return;
    }
    if (bid >= 1792) {
        // ---- Wo cast f32 -> bf16 (for proj_o, which launches later) ----
        const int t = (bid - 1792) * 256 + threadIdx.x;   // [0,4096)
#pragma unroll
        for (int j = 0; j < 4; ++j) {
            const int k = t + j * 4096;                   // float4 idx [0,16384)
            float4 v = reinterpret_cast<const float4*>(Wo)[k];
            bf16x4 o = { (__bf16)v.x, (__bf16)v.y, (__bf16)v.z, (__bf16)v.w };
            reinterpret_cast<bf16x4*>(wob)[k] = o;
        }
        return;
    }
    // ---- QKV projection: f32 X, f32 W (cvt in-reg), N-split 2 ----
    const int pb   = bid - 1024;        // [0,768)
    const int mode = pb >> 8;           // 0=Q,1=K,2=V
    const int mb   = (pb & 255) >> 1;
    const int ny   = pb & 1;
    const float*  X    = (mode == 2) ? xm : xl;
    const float*  W    = (mode == 0) ? Wq : (mode == 1) ? Wk : Wv;
    const float*  bias = (mode == 0) ? bq : (mode == 1) ? bk : bv;
    const float scale  = (mode == 0) ? 0.18033688011112042f : 1.0f; // 0.125*log2(e)

    const int wid  = threadIdx.x >> 6;
    const int lane = threadIdx.x & 63;
    const int g = lane >> 4, c = lane & 15;
    const int m0 = mb * 64 + wid * 16;
    const float* Xp = X + (size_t)m0 * DM;

    f32x4 acc[8];
#pragma unroll
    for (int i = 0; i < 8; ++i) acc[i] = (f32x4){0.f, 0.f, 0.f, 0.f};

#pragma unroll
    for (int kf = 0; kf < 8; ++kf) {
        bf16x8 a = cvt8(Xp + c * DM + kf * 32 + g * 8);
#pragma unroll
        for (int nt = 0; nt < 8; ++nt) {
            bf16x8 b = cvt8(W + (size_t)(ny * 128 + nt * 16 + c) * DM + kf * 32 + g * 8);
            acc[nt] = __builtin_amdgcn_mfma_f32_16x16x32_bf16(a, b, acc[nt], 0, 0, 0);
        }
    }

#pragma unroll
    for (int nt = 0; nt < 8; ++nt) {
        const int n = ny * 128 + nt * 16 + c;
        const float bs = bias[n];
        const int h = n >> 6, d = n & 63;
#pragma unroll
        for (int r = 0; r < 4; ++r) {
            const int m = m0 + g * 4 + r;
            const float v = (acc[nt][r] + bs) * scale;
            const int b_ = m >> 12, s = m & (S_ - 1);
            if (mode == 0)
                Qb[((size_t)(b_ * H_ + h) * S_ + s) * HD_ + d] = (__bf16)v;
            else if (mode == 1)
                Kb[((size_t)(b_ * H_ + h) * S_ + s) * HD_ + d] = (__bf16)v;
            else
                Vtb[((size_t)(b_ * H_ + h) * HD_ + d) * S_ + s] = (__bf16)v;
        }
    }
}

// ---------------- flash attention: 32 q/wave, LDS K/V, in-register P via permlane swaps ----------------
// grid: (B*H, NS, 32); block 256 = 4 waves.
// P redistribution (C-frag -> A-frag) is a 4-lane-group exchange (lanes {c,c+16,c+32,c+48}):
// swap32 then swap16 on word pairs produces the A-frag words directly (no LDS round-trip).
__global__ __launch_bounds__(256, 4) void attn_kernel(const __bf16* __restrict__ Q,
                                                      const __bf16* __restrict__ K,
                                                      const __bf16* __restrict__ Vt,
                                                      const u64* __restrict__ packed,
                                                      __bf16* __restrict__ Opart,
                                                      float* __restrict__ Lpart) {
    __shared__ __bf16 Kt[64][72];      // [kk][d], rows padded to 144B
    __shared__ __bf16 Vl[64][72];      // [d][kk]

    const int bh = blockIdx.x;
    const int sp = blockIdx.y;
    const int qt = blockIdx.z;
    const int tid  = threadIdx.x;
    const int wid  = tid >> 6;
    const int lane = tid & 63;
    const int g = lane >> 4, c = lane & 15;
    const int q0w = qt * 128 + wid * 32;

    // Q B-fragments (col=q, k=d) for both 16-row halves
    const __bf16* Qp = Q + ((size_t)bh * S_ + q0w) * HD_;
    bf16x8 qb[2][2];
#pragma unroll
    for (int qh = 0; qh < 2; ++qh) {
        qb[qh][0] = *reinterpret_cast<const bf16x8*>(Qp + (qh * 16 + c) * HD_ + g * 8);
        qb[qh][1] = *reinterpret_cast<const bf16x8*>(Qp + (qh * 16 + c) * HD_ + 32 + g * 8);
    }

    const __bf16* Kp = K  + (size_t)bh * S_ * HD_;
    const __bf16* Vp = Vt + (size_t)bh * HD_ * S_;

    // staging: thread loads 32B of one row (K: row=kk, V: row=d)
    const int srow = tid >> 2;            // 0..63
    const int sseg = (tid & 3) * 16;      // element col base

    f32x4 o[2][4];
#pragma unroll
    for (int qh = 0; qh < 2; ++qh)
#pragma unroll
        for (int i = 0; i < 4; ++i) o[qh][i] = (f32x4){0.f, 0.f, 0.f, 0.f};
    float rs[2] = {0.f, 0.f};

    const int k0 = sp * KSPAN;

    bf16x8 kr0, kr1, vr0, vr1;
    // prologue: load + write first tile
    {
        const __bf16* krow = Kp + (size_t)(k0 + srow) * HD_ + sseg;
        const __bf16* vrow = Vp + (size_t)srow * S_ + k0 + sseg;
        kr0 = *reinterpret_cast<const bf16x8*>(krow);
        kr1 = *reinterpret_cast<const bf16x8*>(krow + 8);
        vr0 = *reinterpret_cast<const bf16x8*>(vrow);
        vr1 = *reinterpret_cast<const bf16x8*>(vrow + 8);
        *reinterpret_cast<bf16x8*>(&Kt[srow][sseg])     = kr0;
        *reinterpret_cast<bf16x8*>(&Kt[srow][sseg + 8]) = kr1;
        *reinterpret_cast<bf16x8*>(&Vl[srow][sseg])     = vr0;
        *reinterpret_cast<bf16x8*>(&Vl[srow][sseg + 8]) = vr1;
    }
    __syncthreads();

    for (int it = 0; it < NITER; ++it) {
        const int kb = k0 + it * 64;
        const bool more = (it + 1 < NITER);
        // T14: issue next tile's global loads early
        if (more) {
            const __bf16* krow = Kp + (size_t)(kb + 64 + srow) * HD_ + sseg;
            const __bf16* vrow = Vp + (size_t)srow * S_ + kb + 64 + sseg;
            kr0 = *reinterpret_cast<const bf16x8*>(krow);
            kr1 = *reinterpret_cast<const bf16x8*>(krow + 8);
            vr0 = *reinterpret_cast<const bf16x8*>(vrow);
            vr1 = *reinterpret_cast<const bf16x8*>(vrow + 8);
        }

        // mask words for this lane's two q rows
        const u64 mwA = packed[(size_t)(kb >> 6) * S_ + q0w + c];
        const u64 mwB = packed[(size_t)(kb >> 6) * S_ + q0w + 16 + c];

        // ---- S^T = K Q^T : st[nt][qh] covers kk=nt*16..+15 x q=qh*16..+15 ----
        f32x4 st[4][2];
#pragma unroll
        for (int nt = 0; nt < 4; ++nt) {
            bf16x8 ka0 = *reinterpret_cast<const bf16x8*>(&Kt[nt * 16 + c][g * 8]);
            bf16x8 ka1 = *reinterpret_cast<const bf16x8*>(&Kt[nt * 16 + c][32 + g * 8]);
#pragma unroll
            for (int qh = 0; qh < 2; ++qh) {
                f32x4 z = (f32x4){0.f, 0.f, 0.f, 0.f};
                st[nt][qh] = __builtin_amdgcn_mfma_f32_16x16x32_bf16(ka0, qb[qh][0], z, 0, 0, 0);
                st[nt][qh] = __builtin_amdgcn_mfma_f32_16x16x32_bf16(ka1, qb[qh][1], st[nt][qh], 0, 0, 0);
            }
        }

        // ---- softmax + in-register C->A redistribution ----
        bf16x8 pa[2][2];
#pragma unroll
        for (int qh = 0; qh < 2; ++qh) {
            const u64 mw = qh ? mwB : mwA;
            const unsigned wlo = (unsigned)mw, whi = (unsigned)(mw >> 32);
            unsigned W[4][2];
#pragma unroll
            for (int nt = 0; nt < 4; ++nt) {
                const unsigned sh = nt * 4 + g;
                float p0 = ((wlo >> sh) & 1u)        ? exp2f(st[nt][qh][0]) : 0.f;
                float p1 = ((wlo >> (sh + 16)) & 1u) ? exp2f(st[nt][qh][1]) : 0.f;
                float p2 = ((whi >> sh) & 1u)        ? exp2f(st[nt][qh][2]) : 0.f;
                float p3 = ((whi >> (sh + 16)) & 1u) ? exp2f(st[nt][qh][3]) : 0.f;
                rs[qh] += (p0 + p1) + (p2 + p3);
                W[nt][0] = pk2(p0, p1);
                W[nt][1] = pk2(p2, p3);
            }
            // pa0 words: pairs (W[0][h], W[1][h]); pa1: (W[2][h], W[3][h])
            unsigned a0 = W[0][0], b0 = W[1][0];
            asm("v_permlane32_swap_b32 %0, %1" : "+v"(a0), "+v"(b0));
            asm("v_permlane16_swap_b32 %0, %1" : "+v"(a0), "+v"(b0));
            unsigned a1 = W[0][1], b1 = W[1][1];
            asm("v_permlane32_swap_b32 %0, %1" : "+v"(a1), "+v"(b1));
            asm("v_permlane16_swap_b32 %0, %1" : "+v"(a1), "+v"(b1));
            u32x4 w0 = { a0, a1, b0, b1 };          // T0,T1,T2,T3 -> kk g*8+0..7
            pa[qh][0] = __builtin_bit_cast(bf16x8, w0);
            unsigned a2 = W[2][0], b2 = W[3][0];
            asm("v_permlane32_swap_b32 %0, %1" : "+v"(a2), "+v"(b2));
            asm("v_permlane16_swap_b32 %0, %1" : "+v"(a2), "+v"(b2));
            unsigned a3 = W[2][1], b3 = W[3][1];
            asm("v_permlane32_swap_b32 %0, %1" : "+v"(a3), "+v"(b3));
            asm("v_permlane16_swap_b32 %0, %1" : "+v"(a3), "+v"(b3));
            u32x4 w1 = { a2, a3, b2, b3 };          // kk 32 + g*8+0..7
            pa[qh][1] = __builtin_bit_cast(bf16x8, w1);
        }

        // ---- O += P V ----
#pragma unroll
        for (int nt = 0; nt < 4; ++nt) {
            bf16x8 vb0 = *reinterpret_cast<const bf16x8*>(&Vl[nt * 16 + c][g * 8]);
            bf16x8 vb1 = *reinterpret_cast<const bf16x8*>(&Vl[nt * 16 + c][32 + g * 8]);
#pragma unroll
            for (int qh = 0; qh < 2; ++qh) {
                o[qh][nt] = __builtin_amdgcn_mfma_f32_16x16x32_bf16(pa[qh][0], vb0, o[qh][nt], 0, 0, 0);
                o[qh][nt] = __builtin_amdgcn_mfma_f32_16x16x32_bf16(pa[qh][1], vb1, o[qh][nt], 0, 0, 0);
            }
        }

        __syncthreads();
        if (more) {
            *reinterpret_cast<bf16x8*>(&Kt[srow][sseg])     = kr0;
            *reinterpret_cast<bf16x8*>(&Kt[srow][sseg + 8]) = kr1;
            *reinterpret_cast<bf16x8*>(&Vl[srow][sseg])     = vr0;
            *reinterpret_cast<bf16x8*>(&Vl[srow][sseg + 8]) = vr1;
            __syncthreads();
        }
    }

    // ---- epilogue: partial O (bf16) and l (f32) ----
#pragma unroll
    for (int qh = 0; qh < 2; ++qh) {
        rs[qh] += __shfl_xor(rs[qh], 16);
        rs[qh] += __shfl_xor(rs[qh], 32);
    }
    if (lane < 16) {
        Lpart[(size_t)(bh * NS + sp) * S_ + q0w + c]      = rs[0];
        Lpart[(size_t)(bh * NS + sp) * S_ + q0w + 16 + c] = rs[1];
    }

#pragma unroll
    for (int qh = 0; qh < 2; ++qh) {
        const size_t obase = ((size_t)(bh * NS + sp) * S_ + q0w + qh * 16) * 64;
#pragma unroll
        for (int nt = 0; nt < 4; ++nt) {
#pragma unroll
            for (int r = 0; r < 4; ++r)
                Opart[obase + (size_t)(g * 4 + r) * 64 + nt * 16 + c] = (__bf16)o[qh][nt][r];
        }
    }
}

// ---------------- O projection, split-K merge in-register, bf16 Wo, N-split 2 ----------------
// grid (128, 2)
__global__ __launch_bounds__(256) void proj_o_kernel(const __bf16* __restrict__ Opart,
                                                     const float* __restrict__ Lpart,
                                                     const __bf16* __restrict__ wob,
                                                     const float* __restrict__ bo,
                                                     float* __restrict__ out) {
    const int ny   = blockIdx.y;
    const int wid  = threadIdx.x >> 6;
    const int lane = threadIdx.x & 63;
    const int g = lane >> 4, c = lane & 15;
    const int m0 = blockIdx.x * 64 + wid * 16;

    const int row = m0 + c;                    // A-fragment row
    const int b_ = row >> 12, s = row & (S_ - 1);

    f32x4 acc[8];
#pragma unroll
    for (int i = 0; i < 8; ++i) acc[i] = (f32x4){0.f, 0.f, 0.f, 0.f};

#pragma unroll
    for (int kf = 0; kf < 8; ++kf) {
        const int dcol = kf * 32 + g * 8;
        const int h = dcol >> 6, dm = dcol & 63;
        const int bh = b_ * H_ + h;
        float l = 0.f;
        float sum[8] = {0.f, 0.f, 0.f, 0.f, 0.f, 0.f, 0.f, 0.f};
#pragma unroll
        for (int sp = 0; sp < NS; ++sp) {
            l += Lpart[(size_t)(bh * NS + sp) * S_ + s];
            const size_t base = ((size_t)(bh * NS + sp) * S_ + s) * 64 + dm;
            bf16x8 p = *reinterpret_cast<const bf16x8*>(Opart + base);
#pragma unroll
            for (int j = 0; j < 8; ++j) sum[j] += (float)p[j];
        }
        const float invl = 1.0f / l;
        bf16x8 a = { (__bf16)(sum[0] * invl), (__bf16)(sum[1] * invl),
                     (__bf16)(sum[2] * invl), (__bf16)(sum[3] * invl),
                     (__bf16)(sum[4] * invl), (__bf16)(sum[5] * invl),
                     (__bf16)(sum[6] * invl), (__bf16)(sum[7] * invl) };
#pragma unroll
        for (int nt = 0; nt < 8; ++nt) {
            bf16x8 b = *reinterpret_cast<const bf16x8*>(
                wob + (size_t)(ny * 128 + nt * 16 + c) * DM + kf * 32 + g * 8);
            acc[nt] = __builtin_amdgcn_mfma_f32_16x16x32_bf16(a, b, acc[nt], 0, 0, 0);
        }
    }

#pragma unroll
    for (int nt = 0; nt < 8; ++nt) {
        const int n = ny * 128 + nt * 16 + c;
        const float bs = bo[n];
#pragma unroll
        for (int r = 0; r < 4; ++r) {
            const int m = m0 + g * 4 + r;
            out[(size_t)m * DM + n] = acc[nt][r] + bs;
        }
    }
}

// ---------------- launch ----------------
extern "C" void kernel_launch(void* const* d_in, const int* in_sizes, int n_in,
                              void* d_out, int out_size, void* d_ws, size_t ws_size,
                              hipStream_t stream) {
    const float* x_logic  = (const float*)d_in[0];
    const float* x_memory = (const float*)d_in[1];
    const int*   mask     = (const int*)d_in[2];
    const float* Wq = (const float*)d_in[3];
    const float* bq = (const float*)d_in[4];
    const float* Wk = (const float*)d_in[5];
    const float* bk = (const float*)d_in[6];
    const float* Wv = (const float*)d_in[7];
    const float* bv = (const float*)d_in[8];
    const float* Wo = (const float*)d_in[9];
    const float* bo = (const float*)d_in[10];
    float* out = (float*)d_out;

    char* ws = (char*)d_ws;
    size_t off = 0;
    auto alloc = [&](size_t bytes) { char* p = ws + off; off += (bytes + 255) & ~255ull; return p; };

    const size_t NX = (size_t)B_ * S_ * DM;   // 2M elements
    u64*    packed = (u64*)alloc((size_t)S_ * (S_ / 64) * 8);            // 2 MB
    __bf16* wob = (__bf16*)alloc((size_t)DM * DM * 2);
    __bf16* Qb  = (__bf16*)alloc(NX * 2);
    __bf16* Kb  = (__bf16*)alloc(NX * 2);
    __bf16* Vtb = (__bf16*)alloc(NX * 2);
    __bf16* Opart = (__bf16*)alloc((size_t)B_ * H_ * NS * S_ * HD_ * 2); // 16 MB
    float*  Lpart = (float*)alloc((size_t)B_ * H_ * NS * S_ * 4);        // 512 KB

    fused_prep_kernel<<<1808, 256, 0, stream>>>(mask, packed, x_logic, x_memory,
                                                Wq, Wk, Wv, Wo, bq, bk, bv,
                                                Qb, Kb, Vtb, wob);
    attn_kernel<<<dim3(8, NS, 32), 256, 0, stream>>>(Qb, Kb, Vtb, packed, Opart, Lpart);
    proj_o_kernel<<<dim3(128, 2), 256, 0, stream>>>(Opart, Lpart, wob, bo, out);
}

// Round 11
// 143.551 us; speedup vs baseline: 1.4719x; 1.4719x over previous
//
#include <hip/hip_runtime.h>

#define S_  4096
#define HD_ 64
#define H_  4
#define B_  2
#define DM  256
#define NS  4                 // split-K factor for attention
#define KSPAN (S_ / NS)       // 1024
#define NITER (KSPAN / 64)    // 16

typedef __bf16 bf16x8 __attribute__((ext_vector_type(8)));
typedef __bf16 bf16x4 __attribute__((ext_vector_type(4)));
typedef float  f32x4  __attribute__((ext_vector_type(4)));
typedef unsigned long long u64;

__device__ __forceinline__ bf16x8 cvt8(const float* p) {
    float4 u0 = *reinterpret_cast<const float4*>(p);
    float4 u1 = *reinterpret_cast<const float4*>(p + 4);
    bf16x8 r = { (__bf16)u0.x, (__bf16)u0.y, (__bf16)u0.z, (__bf16)u0.w,
                 (__bf16)u1.x, (__bf16)u1.y, (__bf16)u1.z, (__bf16)u1.w };
    return r;
}

// ---------------- mask bit-pack (blocks 0..2047) + weight cast (2048..2111) ----------------
// packed[kbb*S + q] bit layout: bitpos(col) = (col&3)*16 + (col>>2)
__global__ __launch_bounds__(256) void pack_kernel(const int* __restrict__ mask,
                                                   u64* __restrict__ packed,
                                                   const float* __restrict__ Wq,
                                                   const float* __restrict__ Wk,
                                                   const float* __restrict__ Wv,
                                                   const float* __restrict__ Wo,
                                                   __bf16* __restrict__ wqb,
                                                   __bf16* __restrict__ wkb,
                                                   __bf16* __restrict__ wvb,
                                                   __bf16* __restrict__ wob) {
    const int bid = blockIdx.x;
    if (bid < 2048) {
        const int gw   = bid * 4 + (threadIdx.x >> 6);  // [0,8192)
        const int lane = threadIdx.x & 63;
        const int r  = lane >> 4;       // q sub-row 0..3
        const int ll = lane & 15;       // col-quad index
#pragma unroll
        for (int sb = 0; sb < 2; ++sb) {
            int4 v[4];
#pragma unroll
            for (int j = 0; j < 4; ++j) {
                const int u   = gw + (sb * 4 + j) * 8192;   // unit [0,65536)
                const int kbb = u & 63;
                const int q0  = (u >> 6) * 4;
                v[j] = *reinterpret_cast<const int4*>(
                    mask + (size_t)(q0 + r) * S_ + kbb * 64 + ll * 4);
            }
#pragma unroll
            for (int j = 0; j < 4; ++j) {
                const int u   = gw + (sb * 4 + j) * 8192;
                const int kbb = u & 63;
                const int q0  = (u >> 6) * 4;
                const u64 b0 = __ballot(v[j].x != 0);
                const u64 b1 = __ballot(v[j].y != 0);
                const u64 b2 = __ballot(v[j].z != 0);
                const u64 b3 = __ballot(v[j].w != 0);
                if (ll == 0) {
                    const u64 word = ((b0 >> (16 * r)) & 0xFFFFull)
                                   | (((b1 >> (16 * r)) & 0xFFFFull) << 16)
                                   | (((b2 >> (16 * r)) & 0xFFFFull) << 32)
                                   | (((b3 >> (16 * r)) & 0xFFFFull) << 48);
                    packed[(size_t)kbb * S_ + q0 + r] = word;
                }
            }
        }
        return;
    }
    // ---- weight cast: 4 x 65536 f32 -> bf16, streaming float4 ----
    const int t = (bid - 2048) * 256 + threadIdx.x;   // [0,16384)
#pragma unroll
    for (int j = 0; j < 4; ++j) {
        const int idx = t + j * 16384;                // float4 index [0,65536)
        const int arr = idx >> 14, k = idx & 16383;
        const float* src = arr == 0 ? Wq : arr == 1 ? Wk : arr == 2 ? Wv : Wo;
        __bf16* dst      = arr == 0 ? wqb : arr == 1 ? wkb : arr == 2 ? wvb : wob;
        float4 v = reinterpret_cast<const float4*>(src)[k];
        bf16x4 o = { (__bf16)v.x, (__bf16)v.y, (__bf16)v.z, (__bf16)v.w };
        reinterpret_cast<bf16x4*>(dst)[k] = o;
    }
}

// ---------------- QKV projection: f32 X (cvt in-reg), bf16 W, N-split 2 ----------------
// grid (128, 2, 3): x = m-block (64 rows), y = n-half (128 cols), z = 0=Q,1=K,2=V
__global__ __launch_bounds__(256) void proj_qkv_kernel(const float* __restrict__ xl,
                                                       const float* __restrict__ xm,
                                                       const __bf16* __restrict__ wqb,
                                                       const __bf16* __restrict__ wkb,
                                                       const __bf16* __restrict__ wvb,
                                                       const float* __restrict__ bq,
                                                       const float* __restrict__ bk,
                                                       const float* __restrict__ bv,
                                                       __bf16* __restrict__ Qb,
                                                       __bf16* __restrict__ Kb,
                                                       __bf16* __restrict__ Vtb) {
    const int mode = blockIdx.z;
    const int ny   = blockIdx.y;
    const float*  X    = (mode == 2) ? xm : xl;
    const __bf16* W    = (mode == 0) ? wqb : (mode == 1) ? wkb : wvb;
    const float*  bias = (mode == 0) ? bq : (mode == 1) ? bk : bv;
    const float scale  = (mode == 0) ? 0.18033688011112042f : 1.0f; // 0.125*log2(e)

    const int wid  = threadIdx.x >> 6;
    const int lane = threadIdx.x & 63;
    const int g = lane >> 4, c = lane & 15;
    const int m0 = blockIdx.x * 64 + wid * 16;
    const float* Xp = X + (size_t)m0 * DM;

    f32x4 acc[8];
#pragma unroll
    for (int i = 0; i < 8; ++i) acc[i] = (f32x4){0.f, 0.f, 0.f, 0.f};

#pragma unroll
    for (int kf = 0; kf < 8; ++kf) {
        bf16x8 a = cvt8(Xp + c * DM + kf * 32 + g * 8);
#pragma unroll
        for (int nt = 0; nt < 8; ++nt) {
            bf16x8 b = *reinterpret_cast<const bf16x8*>(
                W + (size_t)(ny * 128 + nt * 16 + c) * DM + kf * 32 + g * 8);
            acc[nt] = __builtin_amdgcn_mfma_f32_16x16x32_bf16(a, b, acc[nt], 0, 0, 0);
        }
    }

#pragma unroll
    for (int nt = 0; nt < 8; ++nt) {
        const int n = ny * 128 + nt * 16 + c;
        const float bs = bias[n];
        const int h = n >> 6, d = n & 63;
#pragma unroll
        for (int r = 0; r < 4; ++r) {
            const int m = m0 + g * 4 + r;
            const float v = (acc[nt][r] + bs) * scale;
            const int b_ = m >> 12, s = m & (S_ - 1);
            if (mode == 0)
                Qb[((size_t)(b_ * H_ + h) * S_ + s) * HD_ + d] = (__bf16)v;
            else if (mode == 1)
                Kb[((size_t)(b_ * H_ + h) * S_ + s) * HD_ + d] = (__bf16)v;
            else
                Vtb[((size_t)(b_ * H_ + h) * HD_ + d) * S_ + s] = (__bf16)v;
        }
    }
}

// ---------------- flash attention: 32 q-rows per wave, LDS K/V shared by 4 waves ----------------
// grid: (B*H, NS, 32); block 256 = 4 waves; each wave owns 32 q-rows.
__global__ __launch_bounds__(256, 4) void attn_kernel(const __bf16* __restrict__ Q,
                                                      const __bf16* __restrict__ K,
                                                      const __bf16* __restrict__ Vt,
                                                      const u64* __restrict__ packed,
                                                      __bf16* __restrict__ Opart,
                                                      float* __restrict__ Lpart) {
    __shared__ __bf16 Kt[64][72];      // [kk][d], rows padded to 144B
    __shared__ __bf16 Vl[64][72];      // [d][kk]
    __shared__ __bf16 Pl[4][32][72];   // per-wave P [q][kk]

    const int bh = blockIdx.x;
    const int sp = blockIdx.y;
    const int qt = blockIdx.z;
    const int tid  = threadIdx.x;
    const int wid  = tid >> 6;
    const int lane = tid & 63;
    const int g = lane >> 4, c = lane & 15;
    const int q0w = qt * 128 + wid * 32;

    // Q B-fragments (col=q, k=d) for both 16-row halves
    const __bf16* Qp = Q + ((size_t)bh * S_ + q0w) * HD_;
    bf16x8 qb[2][2];
#pragma unroll
    for (int qh = 0; qh < 2; ++qh) {
        qb[qh][0] = *reinterpret_cast<const bf16x8*>(Qp + (qh * 16 + c) * HD_ + g * 8);
        qb[qh][1] = *reinterpret_cast<const bf16x8*>(Qp + (qh * 16 + c) * HD_ + 32 + g * 8);
    }

    const __bf16* Kp = K  + (size_t)bh * S_ * HD_;
    const __bf16* Vp = Vt + (size_t)bh * HD_ * S_;

    // staging: thread loads 32B of one row (K: row=kk, V: row=d)
    const int srow = tid >> 2;            // 0..63
    const int sseg = (tid & 3) * 16;      // element col base

    f32x4 o[2][4];
#pragma unroll
    for (int qh = 0; qh < 2; ++qh)
#pragma unroll
        for (int i = 0; i < 4; ++i) o[qh][i] = (f32x4){0.f, 0.f, 0.f, 0.f};
    float rs[2] = {0.f, 0.f};

    const int k0 = sp * KSPAN;

    bf16x8 kr0, kr1, vr0, vr1;
    // prologue: load + write first tile
    {
        const __bf16* krow = Kp + (size_t)(k0 + srow) * HD_ + sseg;
        const __bf16* vrow = Vp + (size_t)srow * S_ + k0 + sseg;
        kr0 = *reinterpret_cast<const bf16x8*>(krow);
        kr1 = *reinterpret_cast<const bf16x8*>(krow + 8);
        vr0 = *reinterpret_cast<const bf16x8*>(vrow);
        vr1 = *reinterpret_cast<const bf16x8*>(vrow + 8);
        *reinterpret_cast<bf16x8*>(&Kt[srow][sseg])     = kr0;
        *reinterpret_cast<bf16x8*>(&Kt[srow][sseg + 8]) = kr1;
        *reinterpret_cast<bf16x8*>(&Vl[srow][sseg])     = vr0;
        *reinterpret_cast<bf16x8*>(&Vl[srow][sseg + 8]) = vr1;
    }
    __syncthreads();

    for (int it = 0; it < NITER; ++it) {
        const int kb = k0 + it * 64;
        const bool more = (it + 1 < NITER);
        // T14: issue next tile's global loads early
        if (more) {
            const __bf16* krow = Kp + (size_t)(kb + 64 + srow) * HD_ + sseg;
            const __bf16* vrow = Vp + (size_t)srow * S_ + kb + 64 + sseg;
            kr0 = *reinterpret_cast<const bf16x8*>(krow);
            kr1 = *reinterpret_cast<const bf16x8*>(krow + 8);
            vr0 = *reinterpret_cast<const bf16x8*>(vrow);
            vr1 = *reinterpret_cast<const bf16x8*>(vrow + 8);
        }

        // mask words for this lane's two q rows
        const u64 mwA = packed[(size_t)(kb >> 6) * S_ + q0w + c];
        const u64 mwB = packed[(size_t)(kb >> 6) * S_ + q0w + 16 + c];

        // ---- S^T = K Q^T : st[nt][qh] covers kk=nt*16..+15 x q=qh*16..+15 ----
        f32x4 st[4][2];
        __builtin_amdgcn_s_setprio(1);
#pragma unroll
        for (int nt = 0; nt < 4; ++nt) {
            bf16x8 ka0 = *reinterpret_cast<const bf16x8*>(&Kt[nt * 16 + c][g * 8]);
            bf16x8 ka1 = *reinterpret_cast<const bf16x8*>(&Kt[nt * 16 + c][32 + g * 8]);
#pragma unroll
            for (int qh = 0; qh < 2; ++qh) {
                f32x4 z = (f32x4){0.f, 0.f, 0.f, 0.f};
                st[nt][qh] = __builtin_amdgcn_mfma_f32_16x16x32_bf16(ka0, qb[qh][0], z, 0, 0, 0);
                st[nt][qh] = __builtin_amdgcn_mfma_f32_16x16x32_bf16(ka1, qb[qh][1], st[nt][qh], 0, 0, 0);
            }
        }
        __builtin_amdgcn_s_setprio(0);

        // ---- p = 2^s * bit; bitpos(kk) = (kk&3)*16 + (kk>>2) -> sh = nt*4+g ----
#pragma unroll
        for (int qh = 0; qh < 2; ++qh) {
            const u64 mw = qh ? mwB : mwA;
            const unsigned wlo = (unsigned)mw, whi = (unsigned)(mw >> 32);
#pragma unroll
            for (int nt = 0; nt < 4; ++nt) {
                const unsigned sh = nt * 4 + g;
                float p0 = ((wlo >> sh) & 1u)        ? exp2f(st[nt][qh][0]) : 0.f;
                float p1 = ((wlo >> (sh + 16)) & 1u) ? exp2f(st[nt][qh][1]) : 0.f;
                float p2 = ((whi >> sh) & 1u)        ? exp2f(st[nt][qh][2]) : 0.f;
                float p3 = ((whi >> (sh + 16)) & 1u) ? exp2f(st[nt][qh][3]) : 0.f;
                rs[qh] += (p0 + p1) + (p2 + p3);
                bf16x4 pw = { (__bf16)p0, (__bf16)p1, (__bf16)p2, (__bf16)p3 };
                *reinterpret_cast<bf16x4*>(&Pl[wid][qh * 16 + c][nt * 16 + g * 4]) = pw;
            }
        }

        // ---- P A-fragments (row=q, k=kk) ----
        bf16x8 pa[2][2];
#pragma unroll
        for (int qh = 0; qh < 2; ++qh) {
            pa[qh][0] = *reinterpret_cast<const bf16x8*>(&Pl[wid][qh * 16 + c][g * 8]);
            pa[qh][1] = *reinterpret_cast<const bf16x8*>(&Pl[wid][qh * 16 + c][32 + g * 8]);
        }

        // ---- O += P V ----
        __builtin_amdgcn_s_setprio(1);
#pragma unroll
        for (int nt = 0; nt < 4; ++nt) {
            bf16x8 vb0 = *reinterpret_cast<const bf16x8*>(&Vl[nt * 16 + c][g * 8]);
            bf16x8 vb1 = *reinterpret_cast<const bf16x8*>(&Vl[nt * 16 + c][32 + g * 8]);
#pragma unroll
            for (int qh = 0; qh < 2; ++qh) {
                o[qh][nt] = __builtin_amdgcn_mfma_f32_16x16x32_bf16(pa[qh][0], vb0, o[qh][nt], 0, 0, 0);
                o[qh][nt] = __builtin_amdgcn_mfma_f32_16x16x32_bf16(pa[qh][1], vb1, o[qh][nt], 0, 0, 0);
            }
        }
        __builtin_amdgcn_s_setprio(0);

        __syncthreads();
        if (more) {
            *reinterpret_cast<bf16x8*>(&Kt[srow][sseg])     = kr0;
            *reinterpret_cast<bf16x8*>(&Kt[srow][sseg + 8]) = kr1;
            *reinterpret_cast<bf16x8*>(&Vl[srow][sseg])     = vr0;
            *reinterpret_cast<bf16x8*>(&Vl[srow][sseg + 8]) = vr1;
            __syncthreads();
        }
    }

    // ---- epilogue: partial O (bf16) and l (f32) ----
#pragma unroll
    for (int qh = 0; qh < 2; ++qh) {
        rs[qh] += __shfl_xor(rs[qh], 16);
        rs[qh] += __shfl_xor(rs[qh], 32);
    }
    if (lane < 16) {
        Lpart[(size_t)(bh * NS + sp) * S_ + q0w + c]      = rs[0];
        Lpart[(size_t)(bh * NS + sp) * S_ + q0w + 16 + c] = rs[1];
    }

#pragma unroll
    for (int qh = 0; qh < 2; ++qh) {
        const size_t obase = ((size_t)(bh * NS + sp) * S_ + q0w + qh * 16) * 64;
#pragma unroll
        for (int nt = 0; nt < 4; ++nt) {
#pragma unroll
            for (int r = 0; r < 4; ++r)
                Opart[obase + (size_t)(g * 4 + r) * 64 + nt * 16 + c] = (__bf16)o[qh][nt][r];
        }
    }
}

// ---------------- O projection, split-K merge in-register, bf16 Wo, N-split 2 ----------------
// grid (128, 2)
__global__ __launch_bounds__(256) void proj_o_kernel(const __bf16* __restrict__ Opart,
                                                     const float* __restrict__ Lpart,
                                                     const __bf16* __restrict__ wob,
                                                     const float* __restrict__ bo,
                                                     float* __restrict__ out) {
    const int ny   = blockIdx.y;
    const int wid  = threadIdx.x >> 6;
    const int lane = threadIdx.x & 63;
    const int g = lane >> 4, c = lane & 15;
    const int m0 = blockIdx.x * 64 + wid * 16;

    const int row = m0 + c;                    // A-fragment row
    const int b_ = row >> 12, s = row & (S_ - 1);

    f32x4 acc[8];
#pragma unroll
    for (int i = 0; i < 8; ++i) acc[i] = (f32x4){0.f, 0.f, 0.f, 0.f};

#pragma unroll
    for (int kf = 0; kf < 8; ++kf) {
        const int dcol = kf * 32 + g * 8;
        const int h = dcol >> 6, dm = dcol & 63;
        const int bh = b_ * H_ + h;
        float l = 0.f;
        float sum[8] = {0.f, 0.f, 0.f, 0.f, 0.f, 0.f, 0.f, 0.f};
#pragma unroll
        for (int sp = 0; sp < NS; ++sp) {
            l += Lpart[(size_t)(bh * NS + sp) * S_ + s];
            const size_t base = ((size_t)(bh * NS + sp) * S_ + s) * 64 + dm;
            bf16x8 p = *reinterpret_cast<const bf16x8*>(Opart + base);
#pragma unroll
            for (int j = 0; j < 8; ++j) sum[j] += (float)p[j];
        }
        const float invl = 1.0f / l;
        bf16x8 a = { (__bf16)(sum[0] * invl), (__bf16)(sum[1] * invl),
                     (__bf16)(sum[2] * invl), (__bf16)(sum[3] * invl),
                     (__bf16)(sum[4] * invl), (__bf16)(sum[5] * invl),
                     (__bf16)(sum[6] * invl), (__bf16)(sum[7] * invl) };
#pragma unroll
        for (int nt = 0; nt < 8; ++nt) {
            bf16x8 b = *reinterpret_cast<const bf16x8*>(
                wob + (size_t)(ny * 128 + nt * 16 + c) * DM + kf * 32 + g * 8);
            acc[nt] = __builtin_amdgcn_mfma_f32_16x16x32_bf16(a, b, acc[nt], 0, 0, 0);
        }
    }

#pragma unroll
    for (int nt = 0; nt < 8; ++nt) {
        const int n = ny * 128 + nt * 16 + c;
        const float bs = bo[n];
#pragma unroll
        for (int r = 0; r < 4; ++r) {
            const int m = m0 + g * 4 + r;
            out[(size_t)m * DM + n] = acc[nt][r] + bs;
        }
    }
}

// ---------------- launch ----------------
extern "C" void kernel_launch(void* const* d_in, const int* in_sizes, int n_in,
                              void* d_out, int out_size, void* d_ws, size_t ws_size,
                              hipStream_t stream) {
    const float* x_logic  = (const float*)d_in[0];
    const float* x_memory = (const float*)d_in[1];
    const int*   mask     = (const int*)d_in[2];
    const float* Wq = (const float*)d_in[3];
    const float* bq = (const float*)d_in[4];
    const float* Wk = (const float*)d_in[5];
    const float* bk = (const float*)d_in[6];
    const float* Wv = (const float*)d_in[7];
    const float* bv = (const float*)d_in[8];
    const float* Wo = (const float*)d_in[9];
    const float* bo = (const float*)d_in[10];
    float* out = (float*)d_out;

    char* ws = (char*)d_ws;
    size_t off = 0;
    auto alloc = [&](size_t bytes) { char* p = ws + off; off += (bytes + 255) & ~255ull; return p; };

    const size_t NX = (size_t)B_ * S_ * DM;   // 2M elements
    u64*    packed = (u64*)alloc((size_t)S_ * (S_ / 64) * 8);            // 2 MB
    __bf16* wqb = (__bf16*)alloc((size_t)DM * DM * 2);
    __bf16* wkb = (__bf16*)alloc((size_t)DM * DM * 2);
    __bf16* wvb = (__bf16*)alloc((size_t)DM * DM * 2);
    __bf16* wob = (__bf16*)alloc((size_t)DM * DM * 2);
    __bf16* Qb  = (__bf16*)alloc(NX * 2);
    __bf16* Kb  = (__bf16*)alloc(NX * 2);
    __bf16* Vtb = (__bf16*)alloc(NX * 2);
    __bf16* Opart = (__bf16*)alloc((size_t)B_ * H_ * NS * S_ * HD_ * 2); // 16 MB
    float*  Lpart = (float*)alloc((size_t)B_ * H_ * NS * S_ * 4);        // 512 KB

    pack_kernel<<<2112, 256, 0, stream>>>(mask, packed, Wq, Wk, Wv, Wo, wqb, wkb, wvb, wob);
    proj_qkv_kernel<<<dim3(128, 2, 3), 256, 0, stream>>>(x_logic, x_memory, wqb, wkb, wvb,
                                                         bq, bk, bv, Qb, Kb, Vtb);
    attn_kernel<<<dim3(8, NS, 32), 256, 0, stream>>>(Qb, Kb, Vtb, packed, Opart, Lpart);
    proj_o_kernel<<<dim3(128, 2), 256, 0, stream>>>(Opart, Lpart, wob, bo, out);
}

// Round 12
// 134.596 us; speedup vs baseline: 1.5698x; 1.0665x over previous
//
#include <hip/hip_runtime.h>

#define S_  4096
#define HD_ 64
#define H_  4
#define B_  2
#define DM  256
#define NS  4                 // split-K factor for attention
#define KSPAN (S_ / NS)       // 1024
#define NITER (KSPAN / 64)    // 16

typedef __bf16 bf16x8 __attribute__((ext_vector_type(8)));
typedef __bf16 bf16x4 __attribute__((ext_vector_type(4)));
typedef float  f32x4  __attribute__((ext_vector_type(4)));
typedef unsigned long long u64;

__device__ __forceinline__ bf16x8 cvt8(const float* p) {
    float4 u0 = *reinterpret_cast<const float4*>(p);
    float4 u1 = *reinterpret_cast<const float4*>(p + 4);
    bf16x8 r = { (__bf16)u0.x, (__bf16)u0.y, (__bf16)u0.z, (__bf16)u0.w,
                 (__bf16)u1.x, (__bf16)u1.y, (__bf16)u1.z, (__bf16)u1.w };
    return r;
}

// ---------------- mask bit-pack (blocks 0..2047) + weight cast (2048..2111) ----------------
// packed[kbb*S + q] bit layout: bitpos(col) = (col&3)*16 + (col>>2)
__global__ __launch_bounds__(256) void pack_kernel(const int* __restrict__ mask,
                                                   u64* __restrict__ packed,
                                                   const float* __restrict__ Wq,
                                                   const float* __restrict__ Wk,
                                                   const float* __restrict__ Wv,
                                                   const float* __restrict__ Wo,
                                                   __bf16* __restrict__ wqb,
                                                   __bf16* __restrict__ wkb,
                                                   __bf16* __restrict__ wvb,
                                                   __bf16* __restrict__ wob) {
    const int bid = blockIdx.x;
    if (bid < 2048) {
        const int gw   = bid * 4 + (threadIdx.x >> 6);  // [0,8192)
        const int lane = threadIdx.x & 63;
        const int r  = lane >> 4;       // q sub-row 0..3
        const int ll = lane & 15;       // col-quad index
#pragma unroll
        for (int sb = 0; sb < 2; ++sb) {
            int4 v[4];
#pragma unroll
            for (int j = 0; j < 4; ++j) {
                const int u   = gw + (sb * 4 + j) * 8192;   // unit [0,65536)
                const int kbb = u & 63;
                const int q0  = (u >> 6) * 4;
                v[j] = *reinterpret_cast<const int4*>(
                    mask + (size_t)(q0 + r) * S_ + kbb * 64 + ll * 4);
            }
#pragma unroll
            for (int j = 0; j < 4; ++j) {
                const int u   = gw + (sb * 4 + j) * 8192;
                const int kbb = u & 63;
                const int q0  = (u >> 6) * 4;
                const u64 b0 = __ballot(v[j].x != 0);
                const u64 b1 = __ballot(v[j].y != 0);
                const u64 b2 = __ballot(v[j].z != 0);
                const u64 b3 = __ballot(v[j].w != 0);
                if (ll == 0) {
                    const u64 word = ((b0 >> (16 * r)) & 0xFFFFull)
                                   | (((b1 >> (16 * r)) & 0xFFFFull) << 16)
                                   | (((b2 >> (16 * r)) & 0xFFFFull) << 32)
                                   | (((b3 >> (16 * r)) & 0xFFFFull) << 48);
                    packed[(size_t)kbb * S_ + q0 + r] = word;
                }
            }
        }
        return;
    }
    // ---- weight cast: 4 x 65536 f32 -> bf16, streaming float4 ----
    const int t = (bid - 2048) * 256 + threadIdx.x;   // [0,16384)
#pragma unroll
    for (int j = 0; j < 4; ++j) {
        const int idx = t + j * 16384;                // float4 index [0,65536)
        const int arr = idx >> 14, k = idx & 16383;
        const float* src = arr == 0 ? Wq : arr == 1 ? Wk : arr == 2 ? Wv : Wo;
        __bf16* dst      = arr == 0 ? wqb : arr == 1 ? wkb : arr == 2 ? wvb : wob;
        float4 v = reinterpret_cast<const float4*>(src)[k];
        bf16x4 o = { (__bf16)v.x, (__bf16)v.y, (__bf16)v.z, (__bf16)v.w };
        reinterpret_cast<bf16x4*>(dst)[k] = o;
    }
}

// ---------------- QKV projection: f32 X (cvt in-reg), bf16 W, N-split 2 ----------------
// grid (128, 2, 3): x = m-block (64 rows), y = n-half (128 cols), z = 0=Q,1=K,2=V
__global__ __launch_bounds__(256) void proj_qkv_kernel(const float* __restrict__ xl,
                                                       const float* __restrict__ xm,
                                                       const __bf16* __restrict__ wqb,
                                                       const __bf16* __restrict__ wkb,
                                                       const __bf16* __restrict__ wvb,
                                                       const float* __restrict__ bq,
                                                       const float* __restrict__ bk,
                                                       const float* __restrict__ bv,
                                                       __bf16* __restrict__ Qb,
                                                       __bf16* __restrict__ Kb,
                                                       __bf16* __restrict__ Vtb) {
    const int mode = blockIdx.z;
    const int ny   = blockIdx.y;
    const float*  X    = (mode == 2) ? xm : xl;
    const __bf16* W    = (mode == 0) ? wqb : (mode == 1) ? wkb : wvb;
    const float*  bias = (mode == 0) ? bq : (mode == 1) ? bk : bv;
    const float scale  = (mode == 0) ? 0.18033688011112042f : 1.0f; // 0.125*log2(e)

    const int wid  = threadIdx.x >> 6;
    const int lane = threadIdx.x & 63;
    const int g = lane >> 4, c = lane & 15;
    const int m0 = blockIdx.x * 64 + wid * 16;
    const float* Xp = X + (size_t)m0 * DM;

    f32x4 acc[8];
#pragma unroll
    for (int i = 0; i < 8; ++i) acc[i] = (f32x4){0.f, 0.f, 0.f, 0.f};

#pragma unroll
    for (int kf = 0; kf < 8; ++kf) {
        bf16x8 a = cvt8(Xp + c * DM + kf * 32 + g * 8);
#pragma unroll
        for (int nt = 0; nt < 8; ++nt) {
            bf16x8 b = *reinterpret_cast<const bf16x8*>(
                W + (size_t)(ny * 128 + nt * 16 + c) * DM + kf * 32 + g * 8);
            acc[nt] = __builtin_amdgcn_mfma_f32_16x16x32_bf16(a, b, acc[nt], 0, 0, 0);
        }
    }

#pragma unroll
    for (int nt = 0; nt < 8; ++nt) {
        const int n = ny * 128 + nt * 16 + c;
        const float bs = bias[n];
        const int h = n >> 6, d = n & 63;
#pragma unroll
        for (int r = 0; r < 4; ++r) {
            const int m = m0 + g * 4 + r;
            const float v = (acc[nt][r] + bs) * scale;
            const int b_ = m >> 12, s = m & (S_ - 1);
            if (mode == 0)
                Qb[((size_t)(b_ * H_ + h) * S_ + s) * HD_ + d] = (__bf16)v;
            else if (mode == 1)
                Kb[((size_t)(b_ * H_ + h) * S_ + s) * HD_ + d] = (__bf16)v;
            else
                Vtb[((size_t)(b_ * H_ + h) * HD_ + d) * S_ + s] = (__bf16)v;
        }
    }
}

// ---------------- flash attention: 32 q-rows per wave, LDS K/V shared by 4 waves ----------------
// grid: (B*H, NS, 32); block 256 = 4 waves; each wave owns 32 q-rows.
__global__ __launch_bounds__(256, 4) void attn_kernel(const __bf16* __restrict__ Q,
                                                      const __bf16* __restrict__ K,
                                                      const __bf16* __restrict__ Vt,
                                                      const u64* __restrict__ packed,
                                                      __bf16* __restrict__ Opart,
                                                      float* __restrict__ Lpart) {
    __shared__ __bf16 Kt[64][72];      // [kk][d], rows padded to 144B
    __shared__ __bf16 Vl[64][72];      // [d][kk]
    __shared__ __bf16 Pl[4][32][72];   // per-wave P [q][kk]

    const int bh = blockIdx.x;
    const int sp = blockIdx.y;
    const int qt = blockIdx.z;
    const int tid  = threadIdx.x;
    const int wid  = tid >> 6;
    const int lane = tid & 63;
    const int g = lane >> 4, c = lane & 15;
    const int q0w = qt * 128 + wid * 32;

    // Q B-fragments (col=q, k=d) for both 16-row halves
    const __bf16* Qp = Q + ((size_t)bh * S_ + q0w) * HD_;
    bf16x8 qb[2][2];
#pragma unroll
    for (int qh = 0; qh < 2; ++qh) {
        qb[qh][0] = *reinterpret_cast<const bf16x8*>(Qp + (qh * 16 + c) * HD_ + g * 8);
        qb[qh][1] = *reinterpret_cast<const bf16x8*>(Qp + (qh * 16 + c) * HD_ + 32 + g * 8);
    }

    const __bf16* Kp = K  + (size_t)bh * S_ * HD_;
    const __bf16* Vp = Vt + (size_t)bh * HD_ * S_;

    // staging: thread loads 32B of one row (K: row=kk, V: row=d)
    const int srow = tid >> 2;            // 0..63
    const int sseg = (tid & 3) * 16;      // element col base

    f32x4 o[2][4];
#pragma unroll
    for (int qh = 0; qh < 2; ++qh)
#pragma unroll
        for (int i = 0; i < 4; ++i) o[qh][i] = (f32x4){0.f, 0.f, 0.f, 0.f};
    float rs[2] = {0.f, 0.f};

    const int k0 = sp * KSPAN;

    bf16x8 kr0, kr1, vr0, vr1;
    // prologue: load + write first tile
    {
        const __bf16* krow = Kp + (size_t)(k0 + srow) * HD_ + sseg;
        const __bf16* vrow = Vp + (size_t)srow * S_ + k0 + sseg;
        kr0 = *reinterpret_cast<const bf16x8*>(krow);
        kr1 = *reinterpret_cast<const bf16x8*>(krow + 8);
        vr0 = *reinterpret_cast<const bf16x8*>(vrow);
        vr1 = *reinterpret_cast<const bf16x8*>(vrow + 8);
        *reinterpret_cast<bf16x8*>(&Kt[srow][sseg])     = kr0;
        *reinterpret_cast<bf16x8*>(&Kt[srow][sseg + 8]) = kr1;
        *reinterpret_cast<bf16x8*>(&Vl[srow][sseg])     = vr0;
        *reinterpret_cast<bf16x8*>(&Vl[srow][sseg + 8]) = vr1;
    }
    __syncthreads();

    for (int it = 0; it < NITER; ++it) {
        const int kb = k0 + it * 64;
        const bool more = (it + 1 < NITER);
        // T14: issue next tile's global loads early
        if (more) {
            const __bf16* krow = Kp + (size_t)(kb + 64 + srow) * HD_ + sseg;
            const __bf16* vrow = Vp + (size_t)srow * S_ + kb + 64 + sseg;
            kr0 = *reinterpret_cast<const bf16x8*>(krow);
            kr1 = *reinterpret_cast<const bf16x8*>(krow + 8);
            vr0 = *reinterpret_cast<const bf16x8*>(vrow);
            vr1 = *reinterpret_cast<const bf16x8*>(vrow + 8);
        }

        // mask words for this lane's two q rows
        const u64 mwA = packed[(size_t)(kb >> 6) * S_ + q0w + c];
        const u64 mwB = packed[(size_t)(kb >> 6) * S_ + q0w + 16 + c];

        // ---- S^T = K Q^T : st[nt][qh] covers kk=nt*16..+15 x q=qh*16..+15 ----
        f32x4 st[4][2];
#pragma unroll
        for (int nt = 0; nt < 4; ++nt) {
            bf16x8 ka0 = *reinterpret_cast<const bf16x8*>(&Kt[nt * 16 + c][g * 8]);
            bf16x8 ka1 = *reinterpret_cast<const bf16x8*>(&Kt[nt * 16 + c][32 + g * 8]);
#pragma unroll
            for (int qh = 0; qh < 2; ++qh) {
                f32x4 z = (f32x4){0.f, 0.f, 0.f, 0.f};
                st[nt][qh] = __builtin_amdgcn_mfma_f32_16x16x32_bf16(ka0, qb[qh][0], z, 0, 0, 0);
                st[nt][qh] = __builtin_amdgcn_mfma_f32_16x16x32_bf16(ka1, qb[qh][1], st[nt][qh], 0, 0, 0);
            }
        }

        // ---- p = 2^s * bit; bitpos(kk) = (kk&3)*16 + (kk>>2) -> sh = nt*4+g ----
#pragma unroll
        for (int qh = 0; qh < 2; ++qh) {
            const u64 mw = qh ? mwB : mwA;
            const unsigned wlo = (unsigned)mw, whi = (unsigned)(mw >> 32);
#pragma unroll
            for (int nt = 0; nt < 4; ++nt) {
                const unsigned sh = nt * 4 + g;
                float p0 = ((wlo >> sh) & 1u)        ? exp2f(st[nt][qh][0]) : 0.f;
                float p1 = ((wlo >> (sh + 16)) & 1u) ? exp2f(st[nt][qh][1]) : 0.f;
                float p2 = ((whi >> sh) & 1u)        ? exp2f(st[nt][qh][2]) : 0.f;
                float p3 = ((whi >> (sh + 16)) & 1u) ? exp2f(st[nt][qh][3]) : 0.f;
                rs[qh] += (p0 + p1) + (p2 + p3);
                bf16x4 pw = { (__bf16)p0, (__bf16)p1, (__bf16)p2, (__bf16)p3 };
                *reinterpret_cast<bf16x4*>(&Pl[wid][qh * 16 + c][nt * 16 + g * 4]) = pw;
            }
        }

        // ---- P A-fragments (row=q, k=kk) ----
        bf16x8 pa[2][2];
#pragma unroll
        for (int qh = 0; qh < 2; ++qh) {
            pa[qh][0] = *reinterpret_cast<const bf16x8*>(&Pl[wid][qh * 16 + c][g * 8]);
            pa[qh][1] = *reinterpret_cast<const bf16x8*>(&Pl[wid][qh * 16 + c][32 + g * 8]);
        }

        // ---- O += P V ----
#pragma unroll
        for (int nt = 0; nt < 4; ++nt) {
            bf16x8 vb0 = *reinterpret_cast<const bf16x8*>(&Vl[nt * 16 + c][g * 8]);
            bf16x8 vb1 = *reinterpret_cast<const bf16x8*>(&Vl[nt * 16 + c][32 + g * 8]);
#pragma unroll
            for (int qh = 0; qh < 2; ++qh) {
                o[qh][nt] = __builtin_amdgcn_mfma_f32_16x16x32_bf16(pa[qh][0], vb0, o[qh][nt], 0, 0, 0);
                o[qh][nt] = __builtin_amdgcn_mfma_f32_16x16x32_bf16(pa[qh][1], vb1, o[qh][nt], 0, 0, 0);
            }
        }

        __syncthreads();
        if (more) {
            *reinterpret_cast<bf16x8*>(&Kt[srow][sseg])     = kr0;
            *reinterpret_cast<bf16x8*>(&Kt[srow][sseg + 8]) = kr1;
            *reinterpret_cast<bf16x8*>(&Vl[srow][sseg])     = vr0;
            *reinterpret_cast<bf16x8*>(&Vl[srow][sseg + 8]) = vr1;
            __syncthreads();
        }
    }

    // ---- epilogue: partial O (bf16) and l (f32) ----
#pragma unroll
    for (int qh = 0; qh < 2; ++qh) {
        rs[qh] += __shfl_xor(rs[qh], 16);
        rs[qh] += __shfl_xor(rs[qh], 32);
    }
    if (lane < 16) {
        Lpart[(size_t)(bh * NS + sp) * S_ + q0w + c]      = rs[0];
        Lpart[(size_t)(bh * NS + sp) * S_ + q0w + 16 + c] = rs[1];
    }

#pragma unroll
    for (int qh = 0; qh < 2; ++qh) {
        const size_t obase = ((size_t)(bh * NS + sp) * S_ + q0w + qh * 16) * 64;
#pragma unroll
        for (int nt = 0; nt < 4; ++nt) {
#pragma unroll
            for (int r = 0; r < 4; ++r)
                Opart[obase + (size_t)(g * 4 + r) * 64 + nt * 16 + c] = (__bf16)o[qh][nt][r];
        }
    }
}

// ---------------- O projection, split-K merge in-register, bf16 Wo, N-split 2 ----------------
// grid (128, 2)
__global__ __launch_bounds__(256) void proj_o_kernel(const __bf16* __restrict__ Opart,
                                                     const float* __restrict__ Lpart,
                                                     const __bf16* __restrict__ wob,
                                                     const float* __restrict__ bo,
                                                     float* __restrict__ out) {
    const int ny   = blockIdx.y;
    const int wid  = threadIdx.x >> 6;
    const int lane = threadIdx.x & 63;
    const int g = lane >> 4, c = lane & 15;
    const int m0 = blockIdx.x * 64 + wid * 16;

    const int row = m0 + c;                    // A-fragment row
    const int b_ = row >> 12, s = row & (S_ - 1);

    f32x4 acc[8];
#pragma unroll
    for (int i = 0; i < 8; ++i) acc[i] = (f32x4){0.f, 0.f, 0.f, 0.f};

#pragma unroll
    for (int kf = 0; kf < 8; ++kf) {
        const int dcol = kf * 32 + g * 8;
        const int h = dcol >> 6, dm = dcol & 63;
        const int bh = b_ * H_ + h;
        float l = 0.f;
        float sum[8] = {0.f, 0.f, 0.f, 0.f, 0.f, 0.f, 0.f, 0.f};
#pragma unroll
        for (int sp = 0; sp < NS; ++sp) {
            l += Lpart[(size_t)(bh * NS + sp) * S_ + s];
            const size_t base = ((size_t)(bh * NS + sp) * S_ + s) * 64 + dm;
            bf16x8 p = *reinterpret_cast<const bf16x8*>(Opart + base);
#pragma unroll
            for (int j = 0; j < 8; ++j) sum[j] += (float)p[j];
        }
        const float invl = 1.0f / l;
        bf16x8 a = { (__bf16)(sum[0] * invl), (__bf16)(sum[1] * invl),
                     (__bf16)(sum[2] * invl), (__bf16)(sum[3] * invl),
                     (__bf16)(sum[4] * invl), (__bf16)(sum[5] * invl),
                     (__bf16)(sum[6] * invl), (__bf16)(sum[7] * invl) };
#pragma unroll
        for (int nt = 0; nt < 8; ++nt) {
            bf16x8 b = *reinterpret_cast<const bf16x8*>(
                wob + (size_t)(ny * 128 + nt * 16 + c) * DM + kf * 32 + g * 8);
            acc[nt] = __builtin_amdgcn_mfma_f32_16x16x32_bf16(a, b, acc[nt], 0, 0, 0);
        }
    }

#pragma unroll
    for (int nt = 0; nt < 8; ++nt) {
        const int n = ny * 128 + nt * 16 + c;
        const float bs = bo[n];
#pragma unroll
        for (int r = 0; r < 4; ++r) {
            const int m = m0 + g * 4 + r;
            out[(size_t)m * DM + n] = acc[nt][r] + bs;
        }
    }
}

// ---------------- launch ----------------
extern "C" void kernel_launch(void* const* d_in, const int* in_sizes, int n_in,
                              void* d_out, int out_size, void* d_ws, size_t ws_size,
                              hipStream_t stream) {
    const float* x_logic  = (const float*)d_in[0];
    const float* x_memory = (const float*)d_in[1];
    const int*   mask     = (const int*)d_in[2];
    const float* Wq = (const float*)d_in[3];
    const float* bq = (const float*)d_in[4];
    const float* Wk = (const float*)d_in[5];
    const float* bk = (const float*)d_in[6];
    const float* Wv = (const float*)d_in[7];
    const float* bv = (const float*)d_in[8];
    const float* Wo = (const float*)d_in[9];
    const float* bo = (const float*)d_in[10];
    float* out = (float*)d_out;

    char* ws = (char*)d_ws;
    size_t off = 0;
    auto alloc = [&](size_t bytes) { char* p = ws + off; off += (bytes + 255) & ~255ull; return p; };

    const size_t NX = (size_t)B_ * S_ * DM;   // 2M elements
    u64*    packed = (u64*)alloc((size_t)S_ * (S_ / 64) * 8);            // 2 MB
    __bf16* wqb = (__bf16*)alloc((size_t)DM * DM * 2);
    __bf16* wkb = (__bf16*)alloc((size_t)DM * DM * 2);
    __bf16* wvb = (__bf16*)alloc((size_t)DM * DM * 2);
    __bf16* wob = (__bf16*)alloc((size_t)DM * DM * 2);
    __bf16* Qb  = (__bf16*)alloc(NX * 2);
    __bf16* Kb  = (__bf16*)alloc(NX * 2);
    __bf16* Vtb = (__bf16*)alloc(NX * 2);
    __bf16* Opart = (__bf16*)alloc((size_t)B_ * H_ * NS * S_ * HD_ * 2); // 16 MB
    float*  Lpart = (float*)alloc((size_t)B_ * H_ * NS * S_ * 4);        // 512 KB

    pack_kernel<<<2112, 256, 0, stream>>>(mask, packed, Wq, Wk, Wv, Wo, wqb, wkb, wvb, wob);
    proj_qkv_kernel<<<dim3(128, 2, 3), 256, 0, stream>>>(x_logic, x_memory, wqb, wkb, wvb,
                                                         bq, bk, bv, Qb, Kb, Vtb);
    attn_kernel<<<dim3(8, NS, 32), 256, 0, stream>>>(Qb, Kb, Vtb, packed, Opart, Lpart);
    proj_o_kernel<<<dim3(128, 2), 256, 0, stream>>>(Opart, Lpart, wob, bo, out);
}